// Round 4
// baseline (470.269 us; speedup 1.0000x reference)
//
#include <hip/hip_runtime.h>

// QKNorm MHA: B=2, L=2048, D=2048, H=16, hd=128.
// Round 3 (resubmit after infra failure): (a) fused QKV projection GEMM
// (N=6144, 1536 blocks -> 4 blocks/CU), (b) attention with NO K/V LDS staging
// (L2-resident direct global fragment reads, zero barriers in KV loop),
// XCD-chunked head placement, setprio.

#define DM   2048
#define HD   128
#define NH   16
#define LSEQ 2048
#define NB   2
#define MTOK 4096  // NB*LSEQ
#define QKVS 6144  // fused row stride

typedef __bf16 bf16x8 __attribute__((ext_vector_type(8)));
typedef float  f32x4  __attribute__((ext_vector_type(4)));

__device__ __forceinline__ unsigned short f2bf(float f) {
  unsigned u = __builtin_bit_cast(unsigned, f);
  u += 0x7fffu + ((u >> 16) & 1u);
  return (unsigned short)(u >> 16);
}
__device__ __forceinline__ float bf2f(unsigned short h) {
  unsigned u = ((unsigned)h) << 16;
  return __builtin_bit_cast(float, u);
}
__device__ __forceinline__ void gload16(const unsigned short* gc, unsigned short* l) {
  unsigned short* g = const_cast<unsigned short*>(gc);
  __builtin_amdgcn_global_load_lds((__attribute__((address_space(1))) void*)g,
                                   (__attribute__((address_space(3))) void*)l, 16, 0, 0);
}
__device__ __forceinline__ bf16x8 ld_frag(const void* p) {
  return __builtin_bit_cast(bf16x8, *(const uint4*)p);
}

// ---------------- f32 -> bf16 convert (8 elems/thread) ----------------
__global__ void cvt_bf16_k(const float* __restrict__ s, unsigned short* __restrict__ d, int n8) {
  int i = blockIdx.x * blockDim.x + threadIdx.x;
  if (i >= n8) return;
  const float4* s4 = (const float4*)s;
  float4 a = s4[2 * i], b = s4[2 * i + 1];
  uint4 o;
  o.x = (unsigned)f2bf(a.x) | ((unsigned)f2bf(a.y) << 16);
  o.y = (unsigned)f2bf(a.z) | ((unsigned)f2bf(a.w) << 16);
  o.z = (unsigned)f2bf(b.x) | ((unsigned)f2bf(b.y) << 16);
  o.w = (unsigned)f2bf(b.z) | ((unsigned)f2bf(b.w) << 16);
  ((uint4*)d)[i] = o;
}

// ---------------- bias concat [bq|bk|bv] -> f32[6144] ----------------
__global__ void bcat_k(const float* __restrict__ bq, const float* __restrict__ bk,
                       const float* __restrict__ bv, float* __restrict__ o) {
  int i = blockIdx.x * blockDim.x + threadIdx.x;
  if (i >= QKVS) return;
  float v = (i < 2048) ? bq[i] : (i < 4096) ? bk[i - 2048] : bv[i - 4096];
  o[i] = v;
}

// ---------------- GEMM: C[M,N] = A[M,K] * B[N,K]^T + bias ----------------
template <int OUT_BF16>
__global__ __launch_bounds__(256) void gemm_bt(
    const unsigned short* __restrict__ A, const unsigned short* __restrict__ Bm,
    const float* __restrict__ bias, void* __restrict__ Cv, int M, int N, int K) {
  __shared__ unsigned short As[128 * 32];
  __shared__ unsigned short Bs[128 * 32];
  const int tid = threadIdx.x, wave = tid >> 6, lane = tid & 63;
  const int l15 = lane & 15, l4 = lane >> 4;
  const int wm = wave >> 1, wn = wave & 1;
  const size_t ra0 = (size_t)blockIdx.y * 128;
  const size_t rb0 = (size_t)blockIdx.x * 128;
  f32x4 acc[4][4] = {};
  for (int k0 = 0; k0 < K; k0 += 32) {
    __syncthreads();
#pragma unroll
    for (int i = 0; i < 2; i++) {
      int s = i * 256 + tid;
      int r = s >> 2, c8 = (s & 3) * 8;
      gload16(A + (ra0 + r) * (size_t)K + k0 + c8, &As[(i * 256 + wave * 64) * 8]);
      gload16(Bm + (rb0 + r) * (size_t)K + k0 + c8, &Bs[(i * 256 + wave * 64) * 8]);
    }
    __syncthreads();
    bf16x8 af[4], bfr[4];
#pragma unroll
    for (int mi = 0; mi < 4; mi++) af[mi] = ld_frag(&As[(wm * 64 + mi * 16 + l15) * 32 + l4 * 8]);
#pragma unroll
    for (int ni = 0; ni < 4; ni++) bfr[ni] = ld_frag(&Bs[(wn * 64 + ni * 16 + l15) * 32 + l4 * 8]);
#pragma unroll
    for (int mi = 0; mi < 4; mi++)
#pragma unroll
      for (int ni = 0; ni < 4; ni++)
        acc[mi][ni] = __builtin_amdgcn_mfma_f32_16x16x32_bf16(af[mi], bfr[ni], acc[mi][ni], 0, 0, 0);
  }
  const int col0 = blockIdx.x * 128 + wn * 64;
  const int row0 = blockIdx.y * 128 + wm * 64;
#pragma unroll
  for (int ni = 0; ni < 4; ni++) {
    int col = col0 + ni * 16 + l15;
    float bv = bias[col];
#pragma unroll
    for (int mi = 0; mi < 4; mi++) {
      int row = row0 + mi * 16 + l4 * 4;
#pragma unroll
      for (int r = 0; r < 4; r++) {
        float v = acc[mi][ni][r] + bv;
        if (OUT_BF16)
          ((unsigned short*)Cv)[(size_t)(row + r) * N + col] = f2bf(v);
        else
          ((float*)Cv)[(size_t)(row + r) * N + col] = v;
      }
    }
  }
}

// ------- in-place L2 normalize K rows (strided layout inside qkv) -------
__global__ void qknorm_s_k(unsigned short* __restrict__ qkv) {
  int row = blockIdx.x * 4 + (threadIdx.x >> 6);  // token*16+head
  int lane = threadIdx.x & 63;
  int t = row >> 4, h = row & 15;
  unsigned* p = (unsigned*)(qkv + (size_t)t * QKVS + 2048 + h * HD);
  unsigned w = p[lane];
  float a = bf2f((unsigned short)(w & 0xffff));
  float b = bf2f((unsigned short)(w >> 16));
  float ss = a * a + b * b;
#pragma unroll
  for (int m = 1; m < 64; m <<= 1) ss += __shfl_xor(ss, m);
  float inv = 1.0f / (sqrtf(ss) + 1e-6f);
  p[lane] = (unsigned)f2bf(a * inv) | ((unsigned)f2bf(b * inv) << 16);
}

// ---- V transpose: Vt[bh][d][l] = qkv[b,l][4096 + h*HD + d] ----
__global__ void vtrans_k(const unsigned short* __restrict__ QKV, unsigned short* __restrict__ Vt) {
  __shared__ unsigned short t[128 * 136];
  const int bh = blockIdx.y, b = bh >> 4, h = bh & 15;
  const int l0 = blockIdx.x * 128;
  const int tid = threadIdx.x;
#pragma unroll
  for (int i = 0; i < 8; i++) {
    int s = i * 256 + tid;
    int r = s >> 4, c8 = (s & 15) * 8;
    uint4 v = *(const uint4*)(QKV + ((size_t)(b * LSEQ + l0 + r)) * QKVS + 4096 + h * HD + c8);
    *(uint4*)&t[r * 136 + c8] = v;
  }
  __syncthreads();
#pragma unroll
  for (int i = 0; i < 8; i++) {
    int s = i * 256 + tid;
    int dd = s >> 4, l8 = (s & 15) * 8;
    unsigned short tmp[8];
#pragma unroll
    for (int j = 0; j < 8; j++) tmp[j] = t[(l8 + j) * 136 + dd];
    *(uint4*)(Vt + ((size_t)bh * HD + dd) * LSEQ + l0 + l8) = *(const uint4*)tmp;
  }
}

// ---------------- attention (no K/V staging, no barriers) ----------------
// grid 512 flat; xcd = id&7 owns 4 heads. 4 waves x 32 q-rows, KV tile 64.
__global__ __launch_bounds__(256) void attn2_k(
    const unsigned short* __restrict__ QKV, const unsigned short* __restrict__ Vt,
    unsigned short* __restrict__ Oa) {
  __shared__ unsigned short Ps[4][32 * 64];  // per-wave [q][kv], 16B chunks XOR row&7

  const int id = blockIdx.x;
  const int xcd = id & 7, slot = id >> 3;
  const int bh = xcd * 4 + (slot >> 4);  // 4 heads per XCD (K+V = 4MB = L2)
  const int qb = slot & 15;
  const int b = bh >> 4, h = bh & 15;
  const int q0 = qb * 128;
  const int tid = threadIdx.x, wave = tid >> 6, lane = tid & 63;
  const int l15 = lane & 15, l4 = lane >> 4;
  const int lx = l15 & 7;
  const float scale = 0.08838834764831845f;  // 1/sqrt(128)

  // ---- load Q (32 rows/wave) + fused L2 norm ----
  bf16x8 qf[2][4];
#pragma unroll
  for (int rg = 0; rg < 2; rg++) {
    const unsigned short* qp =
        QKV + ((size_t)(b * LSEQ + q0 + wave * 32 + rg * 16 + l15)) * QKVS + h * HD + l4 * 8;
    uint4 qv[4];
    float qs[4][8];
    float ss = 0.f;
#pragma unroll
    for (int kk = 0; kk < 4; kk++) qv[kk] = *(const uint4*)(qp + kk * 32);
#pragma unroll
    for (int kk = 0; kk < 4; kk++) {
      const unsigned* w = (const unsigned*)&qv[kk];
#pragma unroll
      for (int m = 0; m < 4; m++) {
        float a = bf2f((unsigned short)(w[m] & 0xffff));
        float c = bf2f((unsigned short)(w[m] >> 16));
        qs[kk][2 * m] = a; qs[kk][2 * m + 1] = c;
        ss += a * a + c * c;
      }
    }
    ss += __shfl_xor(ss, 16);
    ss += __shfl_xor(ss, 32);
    float inv = 1.0f / (sqrtf(ss) + 1e-6f);
    uint4 qo;
    unsigned* wo = (unsigned*)&qo;
#pragma unroll
    for (int kk = 0; kk < 4; kk++) {
#pragma unroll
      for (int m = 0; m < 4; m++)
        wo[m] = (unsigned)f2bf(qs[kk][2 * m] * inv) |
                ((unsigned)f2bf(qs[kk][2 * m + 1] * inv) << 16);
      qf[rg][kk] = __builtin_bit_cast(bf16x8, qo);
    }
  }

  f32x4 oacc[2][8] = {};
  float den[2][4] = {};

  const unsigned short* Kb = QKV + ((size_t)(b * LSEQ)) * QKVS + 2048 + h * HD;
  const unsigned short* Vb = Vt + ((size_t)bh * HD) * LSEQ;
  char* pbase = (char*)&Ps[wave][0];

  for (int kv0 = 0; kv0 < LSEQ; kv0 += 64) {
    // ---- QK^T + exp + P store (K fragments straight from L2) ----
#pragma unroll
    for (int ni = 0; ni < 4; ni++) {
      f32x4 s0 = {0.f, 0.f, 0.f, 0.f}, s1 = {0.f, 0.f, 0.f, 0.f};
      const unsigned short* kr = Kb + (size_t)(kv0 + ni * 16 + l15) * QKVS + l4 * 8;
      __builtin_amdgcn_s_setprio(1);
#pragma unroll
      for (int kk = 0; kk < 4; kk++) {
        bf16x8 kf = ld_frag(kr + kk * 32);
        s0 = __builtin_amdgcn_mfma_f32_16x16x32_bf16(qf[0][kk], kf, s0, 0, 0, 0);
        s1 = __builtin_amdgcn_mfma_f32_16x16x32_bf16(qf[1][kk], kf, s1, 0, 0, 0);
      }
      __builtin_amdgcn_s_setprio(0);
      int colb = ((ni * 2 + (l15 >> 3)) << 4) + (l15 & 7) * 2;
#pragma unroll
      for (int r = 0; r < 4; r++) {
        int row = l4 * 4 + r;
        int cs = ((row & 7) << 4);
        float p0 = __expf(s0[r] * scale);
        float p1 = __expf(s1[r] * scale);
        den[0][r] += p0;
        den[1][r] += p1;
        *(unsigned short*)(pbase + row * 128 + (colb ^ cs)) = f2bf(p0);
        *(unsigned short*)(pbase + (16 + row) * 128 + (colb ^ cs)) = f2bf(p1);
      }
    }
    // ---- PV (V fragments straight from L2) ----
#pragma unroll
    for (int ks = 0; ks < 2; ks++) {
      int cx = ((ks * 4 + l4) ^ lx) << 4;
      bf16x8 pf0 = ld_frag(pbase + l15 * 128 + cx);
      bf16x8 pf1 = ld_frag(pbase + (16 + l15) * 128 + cx);
      const unsigned short* vr = Vb + (size_t)l15 * LSEQ + kv0 + ks * 32 + l4 * 8;
      __builtin_amdgcn_s_setprio(1);
#pragma unroll
      for (int d0 = 0; d0 < 8; d0++) {
        bf16x8 vf = ld_frag(vr + (size_t)d0 * 16 * LSEQ);
        oacc[0][d0] = __builtin_amdgcn_mfma_f32_16x16x32_bf16(pf0, vf, oacc[0][d0], 0, 0, 0);
        oacc[1][d0] = __builtin_amdgcn_mfma_f32_16x16x32_bf16(pf1, vf, oacc[1][d0], 0, 0, 0);
      }
      __builtin_amdgcn_s_setprio(0);
    }
  }

  // den: reduce across the 16 lanes (l15) sharing each row
#pragma unroll
  for (int rg = 0; rg < 2; rg++)
#pragma unroll
    for (int r = 0; r < 4; r++) {
      float s = den[rg][r];
      s += __shfl_xor(s, 1);
      s += __shfl_xor(s, 2);
      s += __shfl_xor(s, 4);
      s += __shfl_xor(s, 8);
      den[rg][r] = s;
    }
#pragma unroll
  for (int rg = 0; rg < 2; rg++)
#pragma unroll
    for (int d0 = 0; d0 < 8; d0++)
#pragma unroll
      for (int r = 0; r < 4; r++) {
        float v = oacc[rg][d0][r] / den[rg][r];
        Oa[((size_t)(b * LSEQ + q0 + wave * 32 + rg * 16 + l4 * 4 + r)) * DM + h * HD +
           d0 * 16 + l15] = f2bf(v);
      }
}

extern "C" void kernel_launch(void* const* d_in, const int* in_sizes, int n_in,
                              void* d_out, int out_size, void* d_ws, size_t ws_size,
                              hipStream_t stream) {
  const float* x  = (const float*)d_in[0];
  const float* Wq = (const float*)d_in[1];
  const float* bq = (const float*)d_in[2];
  const float* Wk = (const float*)d_in[3];
  const float* bk = (const float*)d_in[4];
  const float* Wv = (const float*)d_in[5];
  const float* bv = (const float*)d_in[6];
  const float* Wo = (const float*)d_in[7];
  const float* bo = (const float*)d_in[8];

  char* ws = (char*)d_ws;
  unsigned short* xb   = (unsigned short*)(ws + 0);          // 16 MiB; reused as attn-out
  unsigned short* wqkv = (unsigned short*)(ws + 16777216);   // 24 MiB; reused as vt
  unsigned short* wob  = (unsigned short*)(ws + 41943040);   // 8 MiB
  float*          bqkv = (float*)(ws + 50331648);            // 24 KiB
  unsigned short* qkv  = (unsigned short*)(ws + 50364416);   // 48 MiB, end ~96 MiB
  unsigned short* vt   = wqkv;  // alias: weights dead after QKV GEMM
  unsigned short* ao   = xb;    // alias: x dead after QKV GEMM

  // casts
  cvt_bf16_k<<<4096, 256, 0, stream>>>(x, xb, MTOK * DM / 8);
  cvt_bf16_k<<<2048, 256, 0, stream>>>(Wq, wqkv, DM * DM / 8);
  cvt_bf16_k<<<2048, 256, 0, stream>>>(Wk, wqkv + 2048 * 2048, DM * DM / 8);
  cvt_bf16_k<<<2048, 256, 0, stream>>>(Wv, wqkv + 4096 * 2048, DM * DM / 8);
  cvt_bf16_k<<<2048, 256, 0, stream>>>(Wo, wob, DM * DM / 8);
  bcat_k<<<24, 256, 0, stream>>>(bq, bk, bv, bqkv);

  // fused QKV projection: [4096,6144] = xb * wqkv^T + bqkv
  gemm_bt<1><<<dim3(QKVS / 128, MTOK / 128), 256, 0, stream>>>(xb, wqkv, bqkv, qkv,
                                                               MTOK, QKVS, DM);

  // K-norm in place (Q-norm fused in attn)
  qknorm_s_k<<<MTOK * NH / 4, 256, 0, stream>>>(qkv);

  // V transpose per head (into dead weight buffer)
  vtrans_k<<<dim3(LSEQ / 128, NB * NH), 256, 0, stream>>>(qkv, vt);

  // attention
  attn2_k<<<512, 256, 0, stream>>>(qkv, vt, ao);

  // output projection (f32 out)
  gemm_bt<0><<<dim3(DM / 128, MTOK / 128), 256, 0, stream>>>(ao, wob, bo, (float*)d_out,
                                                             MTOK, DM, DM);
}

// Round 5
// 463.388 us; speedup vs baseline: 1.0148x; 1.0148x over previous
//
#include <hip/hip_runtime.h>

// QKNorm MHA: B=2, L=2048, D=2048, H=16, hd=128.
// Round 5: staged-LDS attention with KV-split x2 (grid 1024, 4 blocks/CU),
// KVBLK=32, LDS 24KB, VGPR<=128 (launch_bounds 256,4), bf16 num partials +
// f32 den partials + combine kernel. Fused QKV GEMM kept.

#define DM   2048
#define HD   128
#define NH   16
#define LSEQ 2048
#define NB   2
#define MTOK 4096  // NB*LSEQ
#define QKVS 6144  // fused row stride

typedef __bf16 bf16x8 __attribute__((ext_vector_type(8)));
typedef float  f32x4  __attribute__((ext_vector_type(4)));

__device__ __forceinline__ unsigned short f2bf(float f) {
  unsigned u = __builtin_bit_cast(unsigned, f);
  u += 0x7fffu + ((u >> 16) & 1u);
  return (unsigned short)(u >> 16);
}
__device__ __forceinline__ float bf2f(unsigned short h) {
  unsigned u = ((unsigned)h) << 16;
  return __builtin_bit_cast(float, u);
}
__device__ __forceinline__ void gload16(const unsigned short* gc, unsigned short* l) {
  unsigned short* g = const_cast<unsigned short*>(gc);
  __builtin_amdgcn_global_load_lds((__attribute__((address_space(1))) void*)g,
                                   (__attribute__((address_space(3))) void*)l, 16, 0, 0);
}
__device__ __forceinline__ bf16x8 ld_frag(const void* p) {
  return __builtin_bit_cast(bf16x8, *(const uint4*)p);
}

// ---------------- f32 -> bf16 convert (8 elems/thread) ----------------
__global__ void cvt_bf16_k(const float* __restrict__ s, unsigned short* __restrict__ d, int n8) {
  int i = blockIdx.x * blockDim.x + threadIdx.x;
  if (i >= n8) return;
  const float4* s4 = (const float4*)s;
  float4 a = s4[2 * i], b = s4[2 * i + 1];
  uint4 o;
  o.x = (unsigned)f2bf(a.x) | ((unsigned)f2bf(a.y) << 16);
  o.y = (unsigned)f2bf(a.z) | ((unsigned)f2bf(a.w) << 16);
  o.z = (unsigned)f2bf(b.x) | ((unsigned)f2bf(b.y) << 16);
  o.w = (unsigned)f2bf(b.z) | ((unsigned)f2bf(b.w) << 16);
  ((uint4*)d)[i] = o;
}

// ---------------- bias concat [bq|bk|bv] -> f32[6144] ----------------
__global__ void bcat_k(const float* __restrict__ bq, const float* __restrict__ bk,
                       const float* __restrict__ bv, float* __restrict__ o) {
  int i = blockIdx.x * blockDim.x + threadIdx.x;
  if (i >= QKVS) return;
  float v = (i < 2048) ? bq[i] : (i < 4096) ? bk[i - 2048] : bv[i - 4096];
  o[i] = v;
}

// ---------------- GEMM: C[M,N] = A[M,K] * B[N,K]^T + bias ----------------
template <int OUT_BF16>
__global__ __launch_bounds__(256) void gemm_bt(
    const unsigned short* __restrict__ A, const unsigned short* __restrict__ Bm,
    const float* __restrict__ bias, void* __restrict__ Cv, int M, int N, int K) {
  __shared__ unsigned short As[128 * 32];
  __shared__ unsigned short Bs[128 * 32];
  const int tid = threadIdx.x, wave = tid >> 6, lane = tid & 63;
  const int l15 = lane & 15, l4 = lane >> 4;
  const int wm = wave >> 1, wn = wave & 1;
  const size_t ra0 = (size_t)blockIdx.y * 128;
  const size_t rb0 = (size_t)blockIdx.x * 128;
  f32x4 acc[4][4] = {};
  for (int k0 = 0; k0 < K; k0 += 32) {
    __syncthreads();
#pragma unroll
    for (int i = 0; i < 2; i++) {
      int s = i * 256 + tid;
      int r = s >> 2, c8 = (s & 3) * 8;
      gload16(A + (ra0 + r) * (size_t)K + k0 + c8, &As[(i * 256 + wave * 64) * 8]);
      gload16(Bm + (rb0 + r) * (size_t)K + k0 + c8, &Bs[(i * 256 + wave * 64) * 8]);
    }
    __syncthreads();
    bf16x8 af[4], bfr[4];
#pragma unroll
    for (int mi = 0; mi < 4; mi++) af[mi] = ld_frag(&As[(wm * 64 + mi * 16 + l15) * 32 + l4 * 8]);
#pragma unroll
    for (int ni = 0; ni < 4; ni++) bfr[ni] = ld_frag(&Bs[(wn * 64 + ni * 16 + l15) * 32 + l4 * 8]);
#pragma unroll
    for (int mi = 0; mi < 4; mi++)
#pragma unroll
      for (int ni = 0; ni < 4; ni++)
        acc[mi][ni] = __builtin_amdgcn_mfma_f32_16x16x32_bf16(af[mi], bfr[ni], acc[mi][ni], 0, 0, 0);
  }
  const int col0 = blockIdx.x * 128 + wn * 64;
  const int row0 = blockIdx.y * 128 + wm * 64;
#pragma unroll
  for (int ni = 0; ni < 4; ni++) {
    int col = col0 + ni * 16 + l15;
    float bv = bias[col];
#pragma unroll
    for (int mi = 0; mi < 4; mi++) {
      int row = row0 + mi * 16 + l4 * 4;
#pragma unroll
      for (int r = 0; r < 4; r++) {
        float v = acc[mi][ni][r] + bv;
        if (OUT_BF16)
          ((unsigned short*)Cv)[(size_t)(row + r) * N + col] = f2bf(v);
        else
          ((float*)Cv)[(size_t)(row + r) * N + col] = v;
      }
    }
  }
}

// ------- in-place L2 normalize K rows (strided layout inside qkv) -------
__global__ void qknorm_s_k(unsigned short* __restrict__ qkv) {
  int row = blockIdx.x * 4 + (threadIdx.x >> 6);  // token*16+head
  int lane = threadIdx.x & 63;
  int t = row >> 4, h = row & 15;
  unsigned* p = (unsigned*)(qkv + (size_t)t * QKVS + 2048 + h * HD);
  unsigned w = p[lane];
  float a = bf2f((unsigned short)(w & 0xffff));
  float b = bf2f((unsigned short)(w >> 16));
  float ss = a * a + b * b;
#pragma unroll
  for (int m = 1; m < 64; m <<= 1) ss += __shfl_xor(ss, m);
  float inv = 1.0f / (sqrtf(ss) + 1e-6f);
  p[lane] = (unsigned)f2bf(a * inv) | ((unsigned)f2bf(b * inv) << 16);
}

// ---- V transpose: Vt[bh][d][l] = qkv[b,l][4096 + h*HD + d] ----
__global__ void vtrans_k(const unsigned short* __restrict__ QKV, unsigned short* __restrict__ Vt) {
  __shared__ unsigned short t[128 * 136];
  const int bh = blockIdx.y, b = bh >> 4, h = bh & 15;
  const int l0 = blockIdx.x * 128;
  const int tid = threadIdx.x;
#pragma unroll
  for (int i = 0; i < 8; i++) {
    int s = i * 256 + tid;
    int r = s >> 4, c8 = (s & 15) * 8;
    uint4 v = *(const uint4*)(QKV + ((size_t)(b * LSEQ + l0 + r)) * QKVS + 4096 + h * HD + c8);
    *(uint4*)&t[r * 136 + c8] = v;
  }
  __syncthreads();
#pragma unroll
  for (int i = 0; i < 8; i++) {
    int s = i * 256 + tid;
    int dd = s >> 4, l8 = (s & 15) * 8;
    unsigned short tmp[8];
#pragma unroll
    for (int j = 0; j < 8; j++) tmp[j] = t[(l8 + j) * 136 + dd];
    *(uint4*)(Vt + ((size_t)bh * HD + dd) * LSEQ + l0 + l8) = *(const uint4*)tmp;
  }
}

// ---------------- attention, KV-split x2, staged LDS ----------------
// grid 1024: xcd=id&7 owns 4 heads; per head 2 kvh x 16 qb.
// 4 waves x 32 q-rows, KVBLK=32, LDS 24KB. Writes bf16 num partial + f32 den.
__global__ __launch_bounds__(256, 4) void attn3_k(
    const unsigned short* __restrict__ QKV, const unsigned short* __restrict__ Vt,
    unsigned short* __restrict__ Na, unsigned short* __restrict__ Nb,
    float* __restrict__ Dw) {
  __shared__ unsigned short Ks[32 * 128];   // [kv][d], 16B chunks XOR row&7
  __shared__ unsigned short Vs[128 * 32];   // [d][kv], 16B chunks XOR row&3
  __shared__ unsigned short Ps[4][32 * 32]; // per-wave [q][kv], XOR row&3

  const int id = blockIdx.x;
  const int xcd = id & 7, s = id >> 3;      // s in 0..127
  const int bh = xcd * 4 + (s >> 5);
  const int kvh = (s >> 4) & 1, qb = s & 15;
  const int b = bh >> 4, h = bh & 15;
  const int q0 = qb * 128;
  const int kvbase = kvh * (LSEQ / 2);
  const int tid = threadIdx.x, wave = tid >> 6, lane = tid & 63;
  const int l15 = lane & 15, l4 = lane >> 4;
  const float scale = 0.08838834764831845f;  // 1/sqrt(128)

  // ---- load Q (32 rows/wave) + fused L2 norm ----
  bf16x8 qf[2][4];
#pragma unroll
  for (int rg = 0; rg < 2; rg++) {
    const unsigned short* qp =
        QKV + ((size_t)(b * LSEQ + q0 + wave * 32 + rg * 16 + l15)) * QKVS + h * HD + l4 * 8;
    uint4 qv[4];
    float qs[4][8];
    float ss = 0.f;
#pragma unroll
    for (int kk = 0; kk < 4; kk++) qv[kk] = *(const uint4*)(qp + kk * 32);
#pragma unroll
    for (int kk = 0; kk < 4; kk++) {
      const unsigned* w = (const unsigned*)&qv[kk];
#pragma unroll
      for (int m = 0; m < 4; m++) {
        float a = bf2f((unsigned short)(w[m] & 0xffff));
        float c = bf2f((unsigned short)(w[m] >> 16));
        qs[kk][2 * m] = a; qs[kk][2 * m + 1] = c;
        ss += a * a + c * c;
      }
    }
    ss += __shfl_xor(ss, 16);
    ss += __shfl_xor(ss, 32);
    float inv = 1.0f / (sqrtf(ss) + 1e-6f);
    uint4 qo;
    unsigned* wo = (unsigned*)&qo;
#pragma unroll
    for (int kk = 0; kk < 4; kk++) {
#pragma unroll
      for (int m = 0; m < 4; m++)
        wo[m] = (unsigned)f2bf(qs[kk][2 * m] * inv) |
                ((unsigned)f2bf(qs[kk][2 * m + 1] * inv) << 16);
      qf[rg][kk] = __builtin_bit_cast(bf16x8, qo);
    }
  }

  f32x4 oacc[2][8] = {};
  float den[2][4] = {};
  uint4 pk[2], pv[2];

  const unsigned short* Kb = QKV + ((size_t)(b * LSEQ)) * QKVS + 2048 + h * HD;
  const unsigned short* Vb = Vt + ((size_t)bh * HD) * LSEQ;
  char* pbase = (char*)&Ps[wave][0];
  const int kr0 = tid >> 4, kc = tid & 15;        // K stage coords (i=0: rows 0..15)
  const int vr0 = tid >> 2, vc = tid & 3;         // V stage coords (i=0: rows 0..63)

  // prologue: load tile 0 into regs
#pragma unroll
  for (int i = 0; i < 2; i++) {
    pk[i] = *(const uint4*)(Kb + (size_t)(kvbase + kr0 + i * 16) * QKVS + kc * 8);
    pv[i] = *(const uint4*)(Vb + (size_t)(vr0 + i * 64) * LSEQ + kvbase + vc * 8);
  }

  for (int t = 0; t < 32; t++) {
    const int kv0 = kvbase + t * 32;
    __syncthreads();  // prev-tile readers done
#pragma unroll
    for (int i = 0; i < 2; i++) {
      int kr = kr0 + i * 16;
      *(uint4*)((char*)Ks + kr * 256 + ((kc ^ (kr & 7)) << 4)) = pk[i];
      int vr = vr0 + i * 64;
      *(uint4*)((char*)Vs + vr * 64 + ((vc ^ (vr & 3)) << 4)) = pv[i];
    }
    __syncthreads();

    // ---- QK^T + exp + P store ----
#pragma unroll
    for (int ni = 0; ni < 2; ni++) {
      f32x4 s0 = {0.f, 0.f, 0.f, 0.f}, s1 = {0.f, 0.f, 0.f, 0.f};
      __builtin_amdgcn_s_setprio(1);
#pragma unroll
      for (int kk = 0; kk < 4; kk++) {
        bf16x8 kf = ld_frag((char*)Ks + (ni * 16 + l15) * 256 + (((kk * 4 + l4) ^ (l15 & 7)) << 4));
        s0 = __builtin_amdgcn_mfma_f32_16x16x32_bf16(qf[0][kk], kf, s0, 0, 0, 0);
        s1 = __builtin_amdgcn_mfma_f32_16x16x32_bf16(qf[1][kk], kf, s1, 0, 0, 0);
      }
      __builtin_amdgcn_s_setprio(0);
      int colb = ((ni * 2 + (l15 >> 3)) << 4) + (l15 & 7) * 2;  // chunk byte + in-chunk
#pragma unroll
      for (int r = 0; r < 4; r++) {
        int row = l4 * 4 + r;
        int cs = (row & 3) << 4;
        float p0 = __expf(s0[r] * scale);
        float p1 = __expf(s1[r] * scale);
        den[0][r] += p0;
        den[1][r] += p1;
        *(unsigned short*)(pbase + row * 64 + (colb ^ cs)) = f2bf(p0);
        *(unsigned short*)(pbase + (16 + row) * 64 + (colb ^ cs)) = f2bf(p1);
      }
    }

    // prefetch next tile into regs (hidden under PV)
    if (t + 1 < 32) {
      const int kvn = kv0 + 32;
#pragma unroll
      for (int i = 0; i < 2; i++) {
        pk[i] = *(const uint4*)(Kb + (size_t)(kvn + kr0 + i * 16) * QKVS + kc * 8);
        pv[i] = *(const uint4*)(Vb + (size_t)(vr0 + i * 64) * LSEQ + kvn + vc * 8);
      }
    }

    // ---- PV: oacc += P[32,32] * V[32,128] ----
    int cx = (l4 ^ (l15 & 3)) << 4;
    bf16x8 pf0 = ld_frag(pbase + l15 * 64 + cx);
    bf16x8 pf1 = ld_frag(pbase + (16 + l15) * 64 + cx);
    __builtin_amdgcn_s_setprio(1);
#pragma unroll
    for (int d0 = 0; d0 < 8; d0++) {
      bf16x8 vf = ld_frag((char*)Vs + (d0 * 16 + l15) * 64 + cx);
      oacc[0][d0] = __builtin_amdgcn_mfma_f32_16x16x32_bf16(pf0, vf, oacc[0][d0], 0, 0, 0);
      oacc[1][d0] = __builtin_amdgcn_mfma_f32_16x16x32_bf16(pf1, vf, oacc[1][d0], 0, 0, 0);
    }
    __builtin_amdgcn_s_setprio(0);
  }

  // den: reduce across the 16 l15-lanes sharing each row; write partial
  unsigned short* Np = kvh ? Nb : Na;
#pragma unroll
  for (int rg = 0; rg < 2; rg++)
#pragma unroll
    for (int r = 0; r < 4; r++) {
      float sd = den[rg][r];
      sd += __shfl_xor(sd, 1);
      sd += __shfl_xor(sd, 2);
      sd += __shfl_xor(sd, 4);
      sd += __shfl_xor(sd, 8);
      if (l15 == 0) {
        int token = b * LSEQ + q0 + wave * 32 + rg * 16 + l4 * 4 + r;
        Dw[((size_t)kvh * MTOK + token) * NH + h] = sd;
      }
    }
#pragma unroll
  for (int rg = 0; rg < 2; rg++)
#pragma unroll
    for (int d0 = 0; d0 < 8; d0++)
#pragma unroll
      for (int r = 0; r < 4; r++) {
        int token = b * LSEQ + q0 + wave * 32 + rg * 16 + l4 * 4 + r;
        Np[(size_t)token * DM + h * HD + d0 * 16 + l15] = f2bf(oacc[rg][d0][r]);
      }
}

// ---------------- combine: ao = (n0+n1)/(d0+d1) ----------------
__global__ void comb_k(const unsigned short* __restrict__ Na,
                       const unsigned short* __restrict__ Nb,
                       const float* __restrict__ Dw, unsigned short* __restrict__ Ao) {
  int i = blockIdx.x * 256 + threadIdx.x;  // 1,048,576 total (8 elems each)
  int token = i >> 8, c8 = i & 255;
  int h = c8 >> 4;
  float d = Dw[(size_t)token * NH + h] + Dw[(size_t)(MTOK + token) * NH + h];
  float inv = 1.0f / d;
  uint4 w0 = ((const uint4*)Na)[i];
  uint4 w1 = ((const uint4*)Nb)[i];
  const unsigned* a = (const unsigned*)&w0;
  const unsigned* bq = (const unsigned*)&w1;
  uint4 o;
  unsigned* ow = (unsigned*)&o;
#pragma unroll
  for (int m = 0; m < 4; m++) {
    float lo = (bf2f((unsigned short)(a[m] & 0xffff)) + bf2f((unsigned short)(bq[m] & 0xffff))) * inv;
    float hi = (bf2f((unsigned short)(a[m] >> 16)) + bf2f((unsigned short)(bq[m] >> 16))) * inv;
    ow[m] = (unsigned)f2bf(lo) | ((unsigned)f2bf(hi) << 16);
  }
  ((uint4*)Ao)[i] = o;
}

extern "C" void kernel_launch(void* const* d_in, const int* in_sizes, int n_in,
                              void* d_out, int out_size, void* d_ws, size_t ws_size,
                              hipStream_t stream) {
  const float* x  = (const float*)d_in[0];
  const float* Wq = (const float*)d_in[1];
  const float* bq = (const float*)d_in[2];
  const float* Wk = (const float*)d_in[3];
  const float* bk = (const float*)d_in[4];
  const float* Wv = (const float*)d_in[5];
  const float* bv = (const float*)d_in[6];
  const float* Wo = (const float*)d_in[7];
  const float* bo = (const float*)d_in[8];

  char* ws = (char*)d_ws;
  unsigned short* xb   = (unsigned short*)(ws + 0);          // [0,16M): x bf16 -> num partial A
  unsigned short* wqkv = (unsigned short*)(ws + 16777216);   // [16M,40M): Wq|Wk|Wv bf16
  unsigned short* wob  = (unsigned short*)(ws + 41943040);   // [40M,48M): Wo bf16
  float*          bqkv = (float*)(ws + 50331648);            // [48M,+24K)
  unsigned short* qkv  = (unsigned short*)(ws + 50364416);   // [48.03M,+48M)
  unsigned short* vt   = wqkv;                                // [16M,32M) after QKV gemm
  float*          dwp  = (float*)(ws + 33554432);            // [32M,32.5M) after QKV gemm
  unsigned short* na   = xb;                                  // [0,16M) after QKV gemm
  unsigned short* nb   = (unsigned short*)d_out;              // first 16M of d_out as scratch
  unsigned short* ao   = qkv;                                 // [48.03M,+16M) after attn

  // casts
  cvt_bf16_k<<<4096, 256, 0, stream>>>(x, xb, MTOK * DM / 8);
  cvt_bf16_k<<<2048, 256, 0, stream>>>(Wq, wqkv, DM * DM / 8);
  cvt_bf16_k<<<2048, 256, 0, stream>>>(Wk, wqkv + 2048 * 2048, DM * DM / 8);
  cvt_bf16_k<<<2048, 256, 0, stream>>>(Wv, wqkv + 4096 * 2048, DM * DM / 8);
  cvt_bf16_k<<<2048, 256, 0, stream>>>(Wo, wob, DM * DM / 8);
  bcat_k<<<24, 256, 0, stream>>>(bq, bk, bv, bqkv);

  // fused QKV projection: [4096,6144] = xb * wqkv^T + bqkv
  gemm_bt<1><<<dim3(QKVS / 128, MTOK / 128), 256, 0, stream>>>(xb, wqkv, bqkv, qkv,
                                                               MTOK, QKVS, DM);

  // K-norm in place (Q-norm fused in attn)
  qknorm_s_k<<<MTOK * NH / 4, 256, 0, stream>>>(qkv);

  // V transpose per head (into dead weight buffer)
  vtrans_k<<<dim3(LSEQ / 128, NB * NH), 256, 0, stream>>>(qkv, vt);

  // attention with KV-split x2
  attn3_k<<<1024, 256, 0, stream>>>(qkv, vt, na, nb, dwp);

  // combine partials -> ao (bf16)
  comb_k<<<4096, 256, 0, stream>>>(na, nb, dwp, ao);

  // output projection (f32 out)
  gemm_bt<0><<<dim3(DM / 128, MTOK / 128), 256, 0, stream>>>(ao, wob, bo, (float*)d_out,
                                                             MTOK, DM, DM);
}

// Round 6
// 402.834 us; speedup vs baseline: 1.1674x; 1.1503x over previous
//
#include <hip/hip_runtime.h>

// QKNorm MHA: B=2, L=2048, D=2048, H=16, hd=128.
// Round 6: round-5 structure with the spill bug fixed — attn3_k uses plain
// __launch_bounds__(256) (the (256,4) bound forced 64 VGPRs -> 594 MB of
// scratch spill traffic). Staged-LDS attention, KV-split x2, KVBLK=32.

#define DM   2048
#define HD   128
#define NH   16
#define LSEQ 2048
#define NB   2
#define MTOK 4096  // NB*LSEQ
#define QKVS 6144  // fused row stride

typedef __bf16 bf16x8 __attribute__((ext_vector_type(8)));
typedef float  f32x4  __attribute__((ext_vector_type(4)));

__device__ __forceinline__ unsigned short f2bf(float f) {
  unsigned u = __builtin_bit_cast(unsigned, f);
  u += 0x7fffu + ((u >> 16) & 1u);
  return (unsigned short)(u >> 16);
}
__device__ __forceinline__ float bf2f(unsigned short h) {
  unsigned u = ((unsigned)h) << 16;
  return __builtin_bit_cast(float, u);
}
__device__ __forceinline__ void gload16(const unsigned short* gc, unsigned short* l) {
  unsigned short* g = const_cast<unsigned short*>(gc);
  __builtin_amdgcn_global_load_lds((__attribute__((address_space(1))) void*)g,
                                   (__attribute__((address_space(3))) void*)l, 16, 0, 0);
}
__device__ __forceinline__ bf16x8 ld_frag(const void* p) {
  return __builtin_bit_cast(bf16x8, *(const uint4*)p);
}

// ---------------- f32 -> bf16 convert (8 elems/thread) ----------------
__global__ void cvt_bf16_k(const float* __restrict__ s, unsigned short* __restrict__ d, int n8) {
  int i = blockIdx.x * blockDim.x + threadIdx.x;
  if (i >= n8) return;
  const float4* s4 = (const float4*)s;
  float4 a = s4[2 * i], b = s4[2 * i + 1];
  uint4 o;
  o.x = (unsigned)f2bf(a.x) | ((unsigned)f2bf(a.y) << 16);
  o.y = (unsigned)f2bf(a.z) | ((unsigned)f2bf(a.w) << 16);
  o.z = (unsigned)f2bf(b.x) | ((unsigned)f2bf(b.y) << 16);
  o.w = (unsigned)f2bf(b.z) | ((unsigned)f2bf(b.w) << 16);
  ((uint4*)d)[i] = o;
}

// ---------------- bias concat [bq|bk|bv] -> f32[6144] ----------------
__global__ void bcat_k(const float* __restrict__ bq, const float* __restrict__ bk,
                       const float* __restrict__ bv, float* __restrict__ o) {
  int i = blockIdx.x * blockDim.x + threadIdx.x;
  if (i >= QKVS) return;
  float v = (i < 2048) ? bq[i] : (i < 4096) ? bk[i - 2048] : bv[i - 4096];
  o[i] = v;
}

// ---------------- GEMM: C[M,N] = A[M,K] * B[N,K]^T + bias ----------------
template <int OUT_BF16>
__global__ __launch_bounds__(256) void gemm_bt(
    const unsigned short* __restrict__ A, const unsigned short* __restrict__ Bm,
    const float* __restrict__ bias, void* __restrict__ Cv, int M, int N, int K) {
  __shared__ unsigned short As[128 * 32];
  __shared__ unsigned short Bs[128 * 32];
  const int tid = threadIdx.x, wave = tid >> 6, lane = tid & 63;
  const int l15 = lane & 15, l4 = lane >> 4;
  const int wm = wave >> 1, wn = wave & 1;
  const size_t ra0 = (size_t)blockIdx.y * 128;
  const size_t rb0 = (size_t)blockIdx.x * 128;
  f32x4 acc[4][4] = {};
  for (int k0 = 0; k0 < K; k0 += 32) {
    __syncthreads();
#pragma unroll
    for (int i = 0; i < 2; i++) {
      int s = i * 256 + tid;
      int r = s >> 2, c8 = (s & 3) * 8;
      gload16(A + (ra0 + r) * (size_t)K + k0 + c8, &As[(i * 256 + wave * 64) * 8]);
      gload16(Bm + (rb0 + r) * (size_t)K + k0 + c8, &Bs[(i * 256 + wave * 64) * 8]);
    }
    __syncthreads();
    bf16x8 af[4], bfr[4];
#pragma unroll
    for (int mi = 0; mi < 4; mi++) af[mi] = ld_frag(&As[(wm * 64 + mi * 16 + l15) * 32 + l4 * 8]);
#pragma unroll
    for (int ni = 0; ni < 4; ni++) bfr[ni] = ld_frag(&Bs[(wn * 64 + ni * 16 + l15) * 32 + l4 * 8]);
#pragma unroll
    for (int mi = 0; mi < 4; mi++)
#pragma unroll
      for (int ni = 0; ni < 4; ni++)
        acc[mi][ni] = __builtin_amdgcn_mfma_f32_16x16x32_bf16(af[mi], bfr[ni], acc[mi][ni], 0, 0, 0);
  }
  const int col0 = blockIdx.x * 128 + wn * 64;
  const int row0 = blockIdx.y * 128 + wm * 64;
#pragma unroll
  for (int ni = 0; ni < 4; ni++) {
    int col = col0 + ni * 16 + l15;
    float bv = bias[col];
#pragma unroll
    for (int mi = 0; mi < 4; mi++) {
      int row = row0 + mi * 16 + l4 * 4;
#pragma unroll
      for (int r = 0; r < 4; r++) {
        float v = acc[mi][ni][r] + bv;
        if (OUT_BF16)
          ((unsigned short*)Cv)[(size_t)(row + r) * N + col] = f2bf(v);
        else
          ((float*)Cv)[(size_t)(row + r) * N + col] = v;
      }
    }
  }
}

// ------- in-place L2 normalize K rows (strided layout inside qkv) -------
__global__ void qknorm_s_k(unsigned short* __restrict__ qkv) {
  int row = blockIdx.x * 4 + (threadIdx.x >> 6);  // token*16+head
  int lane = threadIdx.x & 63;
  int t = row >> 4, h = row & 15;
  unsigned* p = (unsigned*)(qkv + (size_t)t * QKVS + 2048 + h * HD);
  unsigned w = p[lane];
  float a = bf2f((unsigned short)(w & 0xffff));
  float b = bf2f((unsigned short)(w >> 16));
  float ss = a * a + b * b;
#pragma unroll
  for (int m = 1; m < 64; m <<= 1) ss += __shfl_xor(ss, m);
  float inv = 1.0f / (sqrtf(ss) + 1e-6f);
  p[lane] = (unsigned)f2bf(a * inv) | ((unsigned)f2bf(b * inv) << 16);
}

// ---- V transpose: Vt[bh][d][l] = qkv[b,l][4096 + h*HD + d] ----
__global__ void vtrans_k(const unsigned short* __restrict__ QKV, unsigned short* __restrict__ Vt) {
  __shared__ unsigned short t[128 * 136];
  const int bh = blockIdx.y, b = bh >> 4, h = bh & 15;
  const int l0 = blockIdx.x * 128;
  const int tid = threadIdx.x;
#pragma unroll
  for (int i = 0; i < 8; i++) {
    int s = i * 256 + tid;
    int r = s >> 4, c8 = (s & 15) * 8;
    uint4 v = *(const uint4*)(QKV + ((size_t)(b * LSEQ + l0 + r)) * QKVS + 4096 + h * HD + c8);
    *(uint4*)&t[r * 136 + c8] = v;
  }
  __syncthreads();
#pragma unroll
  for (int i = 0; i < 8; i++) {
    int s = i * 256 + tid;
    int dd = s >> 4, l8 = (s & 15) * 8;
    unsigned short tmp[8];
#pragma unroll
    for (int j = 0; j < 8; j++) tmp[j] = t[(l8 + j) * 136 + dd];
    *(uint4*)(Vt + ((size_t)bh * HD + dd) * LSEQ + l0 + l8) = *(const uint4*)tmp;
  }
}

// ---------------- attention, KV-split x2, staged LDS ----------------
// grid 1024: xcd=id&7 owns 4 heads; per head 2 kvh x 16 qb.
// 4 waves x 32 q-rows, KVBLK=32, LDS 24KB. Writes bf16 num partial + f32 den.
__global__ __launch_bounds__(256) void attn3_k(
    const unsigned short* __restrict__ QKV, const unsigned short* __restrict__ Vt,
    unsigned short* __restrict__ Na, unsigned short* __restrict__ Nb,
    float* __restrict__ Dw) {
  __shared__ unsigned short Ks[32 * 128];   // [kv][d], 16B chunks XOR row&7
  __shared__ unsigned short Vs[128 * 32];   // [d][kv], 16B chunks XOR row&3
  __shared__ unsigned short Ps[4][32 * 32]; // per-wave [q][kv], XOR row&3

  const int id = blockIdx.x;
  const int xcd = id & 7, s = id >> 3;      // s in 0..127
  const int bh = xcd * 4 + (s >> 5);
  const int kvh = (s >> 4) & 1, qb = s & 15;
  const int b = bh >> 4, h = bh & 15;
  const int q0 = qb * 128;
  const int kvbase = kvh * (LSEQ / 2);
  const int tid = threadIdx.x, wave = tid >> 6, lane = tid & 63;
  const int l15 = lane & 15, l4 = lane >> 4;
  const float scale = 0.08838834764831845f;  // 1/sqrt(128)

  // ---- load Q (32 rows/wave) + fused L2 norm ----
  bf16x8 qf[2][4];
#pragma unroll
  for (int rg = 0; rg < 2; rg++) {
    const unsigned short* qp =
        QKV + ((size_t)(b * LSEQ + q0 + wave * 32 + rg * 16 + l15)) * QKVS + h * HD + l4 * 8;
    uint4 qv[4];
    float qs[4][8];
    float ss = 0.f;
#pragma unroll
    for (int kk = 0; kk < 4; kk++) qv[kk] = *(const uint4*)(qp + kk * 32);
#pragma unroll
    for (int kk = 0; kk < 4; kk++) {
      const unsigned* w = (const unsigned*)&qv[kk];
#pragma unroll
      for (int m = 0; m < 4; m++) {
        float a = bf2f((unsigned short)(w[m] & 0xffff));
        float c = bf2f((unsigned short)(w[m] >> 16));
        qs[kk][2 * m] = a; qs[kk][2 * m + 1] = c;
        ss += a * a + c * c;
      }
    }
    ss += __shfl_xor(ss, 16);
    ss += __shfl_xor(ss, 32);
    float inv = 1.0f / (sqrtf(ss) + 1e-6f);
    uint4 qo;
    unsigned* wo = (unsigned*)&qo;
#pragma unroll
    for (int kk = 0; kk < 4; kk++) {
#pragma unroll
      for (int m = 0; m < 4; m++)
        wo[m] = (unsigned)f2bf(qs[kk][2 * m] * inv) |
                ((unsigned)f2bf(qs[kk][2 * m + 1] * inv) << 16);
      qf[rg][kk] = __builtin_bit_cast(bf16x8, qo);
    }
  }

  f32x4 oacc[2][8] = {};
  float den[2][4] = {};
  uint4 pk[2], pv[2];

  const unsigned short* Kb = QKV + ((size_t)(b * LSEQ)) * QKVS + 2048 + h * HD;
  const unsigned short* Vb = Vt + ((size_t)bh * HD) * LSEQ;
  char* pbase = (char*)&Ps[wave][0];
  const int kr0 = tid >> 4, kc = tid & 15;        // K stage coords (i=0: rows 0..15)
  const int vr0 = tid >> 2, vc = tid & 3;         // V stage coords (i=0: rows 0..63)

  // prologue: load tile 0 into regs
#pragma unroll
  for (int i = 0; i < 2; i++) {
    pk[i] = *(const uint4*)(Kb + (size_t)(kvbase + kr0 + i * 16) * QKVS + kc * 8);
    pv[i] = *(const uint4*)(Vb + (size_t)(vr0 + i * 64) * LSEQ + kvbase + vc * 8);
  }

  for (int t = 0; t < 32; t++) {
    const int kv0 = kvbase + t * 32;
    __syncthreads();  // prev-tile readers done
#pragma unroll
    for (int i = 0; i < 2; i++) {
      int kr = kr0 + i * 16;
      *(uint4*)((char*)Ks + kr * 256 + ((kc ^ (kr & 7)) << 4)) = pk[i];
      int vr = vr0 + i * 64;
      *(uint4*)((char*)Vs + vr * 64 + ((vc ^ (vr & 3)) << 4)) = pv[i];
    }
    __syncthreads();

    // ---- QK^T + exp + P store ----
#pragma unroll
    for (int ni = 0; ni < 2; ni++) {
      f32x4 s0 = {0.f, 0.f, 0.f, 0.f}, s1 = {0.f, 0.f, 0.f, 0.f};
      __builtin_amdgcn_s_setprio(1);
#pragma unroll
      for (int kk = 0; kk < 4; kk++) {
        bf16x8 kf = ld_frag((char*)Ks + (ni * 16 + l15) * 256 + (((kk * 4 + l4) ^ (l15 & 7)) << 4));
        s0 = __builtin_amdgcn_mfma_f32_16x16x32_bf16(qf[0][kk], kf, s0, 0, 0, 0);
        s1 = __builtin_amdgcn_mfma_f32_16x16x32_bf16(qf[1][kk], kf, s1, 0, 0, 0);
      }
      __builtin_amdgcn_s_setprio(0);
      int colb = ((ni * 2 + (l15 >> 3)) << 4) + (l15 & 7) * 2;  // chunk byte + in-chunk
#pragma unroll
      for (int r = 0; r < 4; r++) {
        int row = l4 * 4 + r;
        int cs = (row & 3) << 4;
        float p0 = __expf(s0[r] * scale);
        float p1 = __expf(s1[r] * scale);
        den[0][r] += p0;
        den[1][r] += p1;
        *(unsigned short*)(pbase + row * 64 + (colb ^ cs)) = f2bf(p0);
        *(unsigned short*)(pbase + (16 + row) * 64 + (colb ^ cs)) = f2bf(p1);
      }
    }

    // prefetch next tile into regs (hidden under PV)
    if (t + 1 < 32) {
      const int kvn = kv0 + 32;
#pragma unroll
      for (int i = 0; i < 2; i++) {
        pk[i] = *(const uint4*)(Kb + (size_t)(kvn + kr0 + i * 16) * QKVS + kc * 8);
        pv[i] = *(const uint4*)(Vb + (size_t)(vr0 + i * 64) * LSEQ + kvn + vc * 8);
      }
    }

    // ---- PV: oacc += P[32,32] * V[32,128] ----
    int cx = (l4 ^ (l15 & 3)) << 4;
    bf16x8 pf0 = ld_frag(pbase + l15 * 64 + cx);
    bf16x8 pf1 = ld_frag(pbase + (16 + l15) * 64 + cx);
    __builtin_amdgcn_s_setprio(1);
#pragma unroll
    for (int d0 = 0; d0 < 8; d0++) {
      bf16x8 vf = ld_frag((char*)Vs + (d0 * 16 + l15) * 64 + cx);
      oacc[0][d0] = __builtin_amdgcn_mfma_f32_16x16x32_bf16(pf0, vf, oacc[0][d0], 0, 0, 0);
      oacc[1][d0] = __builtin_amdgcn_mfma_f32_16x16x32_bf16(pf1, vf, oacc[1][d0], 0, 0, 0);
    }
    __builtin_amdgcn_s_setprio(0);
  }

  // den: reduce across the 16 l15-lanes sharing each row; write partial
  unsigned short* Np = kvh ? Nb : Na;
#pragma unroll
  for (int rg = 0; rg < 2; rg++)
#pragma unroll
    for (int r = 0; r < 4; r++) {
      float sd = den[rg][r];
      sd += __shfl_xor(sd, 1);
      sd += __shfl_xor(sd, 2);
      sd += __shfl_xor(sd, 4);
      sd += __shfl_xor(sd, 8);
      if (l15 == 0) {
        int token = b * LSEQ + q0 + wave * 32 + rg * 16 + l4 * 4 + r;
        Dw[((size_t)kvh * MTOK + token) * NH + h] = sd;
      }
    }
#pragma unroll
  for (int rg = 0; rg < 2; rg++)
#pragma unroll
    for (int d0 = 0; d0 < 8; d0++)
#pragma unroll
      for (int r = 0; r < 4; r++) {
        int token = b * LSEQ + q0 + wave * 32 + rg * 16 + l4 * 4 + r;
        Np[(size_t)token * DM + h * HD + d0 * 16 + l15] = f2bf(oacc[rg][d0][r]);
      }
}

// ---------------- combine: ao = (n0+n1)/(d0+d1) ----------------
__global__ void comb_k(const unsigned short* __restrict__ Na,
                       const unsigned short* __restrict__ Nb,
                       const float* __restrict__ Dw, unsigned short* __restrict__ Ao) {
  int i = blockIdx.x * 256 + threadIdx.x;  // 1,048,576 total (8 elems each)
  int token = i >> 8, c8 = i & 255;
  int h = c8 >> 4;
  float d = Dw[(size_t)token * NH + h] + Dw[(size_t)(MTOK + token) * NH + h];
  float inv = 1.0f / d;
  uint4 w0 = ((const uint4*)Na)[i];
  uint4 w1 = ((const uint4*)Nb)[i];
  const unsigned* a = (const unsigned*)&w0;
  const unsigned* bq = (const unsigned*)&w1;
  uint4 o;
  unsigned* ow = (unsigned*)&o;
#pragma unroll
  for (int m = 0; m < 4; m++) {
    float lo = (bf2f((unsigned short)(a[m] & 0xffff)) + bf2f((unsigned short)(bq[m] & 0xffff))) * inv;
    float hi = (bf2f((unsigned short)(a[m] >> 16)) + bf2f((unsigned short)(bq[m] >> 16))) * inv;
    ow[m] = (unsigned)f2bf(lo) | ((unsigned)f2bf(hi) << 16);
  }
  ((uint4*)Ao)[i] = o;
}

extern "C" void kernel_launch(void* const* d_in, const int* in_sizes, int n_in,
                              void* d_out, int out_size, void* d_ws, size_t ws_size,
                              hipStream_t stream) {
  const float* x  = (const float*)d_in[0];
  const float* Wq = (const float*)d_in[1];
  const float* bq = (const float*)d_in[2];
  const float* Wk = (const float*)d_in[3];
  const float* bk = (const float*)d_in[4];
  const float* Wv = (const float*)d_in[5];
  const float* bv = (const float*)d_in[6];
  const float* Wo = (const float*)d_in[7];
  const float* bo = (const float*)d_in[8];

  char* ws = (char*)d_ws;
  unsigned short* xb   = (unsigned short*)(ws + 0);          // [0,16M): x bf16 -> num partial A
  unsigned short* wqkv = (unsigned short*)(ws + 16777216);   // [16M,40M): Wq|Wk|Wv bf16
  unsigned short* wob  = (unsigned short*)(ws + 41943040);   // [40M,48M): Wo bf16
  float*          bqkv = (float*)(ws + 50331648);            // [48M,+24K)
  unsigned short* qkv  = (unsigned short*)(ws + 50364416);   // [48.03M,+48M)
  unsigned short* vt   = wqkv;                                // [16M,32M) after QKV gemm
  float*          dwp  = (float*)(ws + 33554432);            // [32M,32.5M) after QKV gemm
  unsigned short* na   = xb;                                  // [0,16M) after QKV gemm
  unsigned short* nb   = (unsigned short*)d_out;              // first 16M of d_out as scratch
  unsigned short* ao   = qkv;                                 // [48.03M,+16M) after attn

  // casts
  cvt_bf16_k<<<4096, 256, 0, stream>>>(x, xb, MTOK * DM / 8);
  cvt_bf16_k<<<2048, 256, 0, stream>>>(Wq, wqkv, DM * DM / 8);
  cvt_bf16_k<<<2048, 256, 0, stream>>>(Wk, wqkv + 2048 * 2048, DM * DM / 8);
  cvt_bf16_k<<<2048, 256, 0, stream>>>(Wv, wqkv + 4096 * 2048, DM * DM / 8);
  cvt_bf16_k<<<2048, 256, 0, stream>>>(Wo, wob, DM * DM / 8);
  bcat_k<<<24, 256, 0, stream>>>(bq, bk, bv, bqkv);

  // fused QKV projection: [4096,6144] = xb * wqkv^T + bqkv
  gemm_bt<1><<<dim3(QKVS / 128, MTOK / 128), 256, 0, stream>>>(xb, wqkv, bqkv, qkv,
                                                               MTOK, QKVS, DM);

  // K-norm in place (Q-norm fused in attn)
  qknorm_s_k<<<MTOK * NH / 4, 256, 0, stream>>>(qkv);

  // V transpose per head (into dead weight buffer)
  vtrans_k<<<dim3(LSEQ / 128, NB * NH), 256, 0, stream>>>(qkv, vt);

  // attention with KV-split x2
  attn3_k<<<1024, 256, 0, stream>>>(qkv, vt, na, nb, dwp);

  // combine partials -> ao (bf16)
  comb_k<<<4096, 256, 0, stream>>>(na, nb, dwp, ao);

  // output projection (f32 out)
  gemm_bt<0><<<dim3(DM / 128, MTOK / 128), 256, 0, stream>>>(ao, wob, bo, (float*)d_out,
                                                             MTOK, DM, DM);
}

// Round 7
// 358.690 us; speedup vs baseline: 1.3111x; 1.1231x over previous
//
#include <hip/hip_runtime.h>

// QKNorm MHA: B=2, L=2048, D=2048, H=16, hd=128.
// Round 7: attention restructured — swapped QK^T (P stays in registers,
// shuffle redistribution to PV A-operand; no P LDS), single-barrier
// double-buffered K/V staging, Vs 80B pitch (conflict-free), KV-split x2.

#define DM   2048
#define HD   128
#define NH   16
#define LSEQ 2048
#define NB   2
#define MTOK 4096  // NB*LSEQ
#define QKVS 6144  // fused row stride

typedef __bf16 bf16x8 __attribute__((ext_vector_type(8)));
typedef float  f32x4  __attribute__((ext_vector_type(4)));

__device__ __forceinline__ unsigned short f2bf(float f) {
  unsigned u = __builtin_bit_cast(unsigned, f);
  u += 0x7fffu + ((u >> 16) & 1u);
  return (unsigned short)(u >> 16);
}
__device__ __forceinline__ unsigned packbf(float lo, float hi) {
  return (unsigned)f2bf(lo) | ((unsigned)f2bf(hi) << 16);
}
__device__ __forceinline__ float bf2f(unsigned short h) {
  unsigned u = ((unsigned)h) << 16;
  return __builtin_bit_cast(float, u);
}
__device__ __forceinline__ void gload16(const unsigned short* gc, unsigned short* l) {
  unsigned short* g = const_cast<unsigned short*>(gc);
  __builtin_amdgcn_global_load_lds((__attribute__((address_space(1))) void*)g,
                                   (__attribute__((address_space(3))) void*)l, 16, 0, 0);
}
__device__ __forceinline__ bf16x8 ld_frag(const void* p) {
  return __builtin_bit_cast(bf16x8, *(const uint4*)p);
}

// ---------------- f32 -> bf16 convert (8 elems/thread) ----------------
__global__ void cvt_bf16_k(const float* __restrict__ s, unsigned short* __restrict__ d, int n8) {
  int i = blockIdx.x * blockDim.x + threadIdx.x;
  if (i >= n8) return;
  const float4* s4 = (const float4*)s;
  float4 a = s4[2 * i], b = s4[2 * i + 1];
  uint4 o;
  o.x = packbf(a.x, a.y);
  o.y = packbf(a.z, a.w);
  o.z = packbf(b.x, b.y);
  o.w = packbf(b.z, b.w);
  ((uint4*)d)[i] = o;
}

// ---------------- bias concat [bq|bk|bv] -> f32[6144] ----------------
__global__ void bcat_k(const float* __restrict__ bq, const float* __restrict__ bk,
                       const float* __restrict__ bv, float* __restrict__ o) {
  int i = blockIdx.x * blockDim.x + threadIdx.x;
  if (i >= QKVS) return;
  float v = (i < 2048) ? bq[i] : (i < 4096) ? bk[i - 2048] : bv[i - 4096];
  o[i] = v;
}

// ---------------- GEMM: C[M,N] = A[M,K] * B[N,K]^T + bias ----------------
template <int OUT_BF16>
__global__ __launch_bounds__(256) void gemm_bt(
    const unsigned short* __restrict__ A, const unsigned short* __restrict__ Bm,
    const float* __restrict__ bias, void* __restrict__ Cv, int M, int N, int K) {
  __shared__ unsigned short As[128 * 32];
  __shared__ unsigned short Bs[128 * 32];
  const int tid = threadIdx.x, wave = tid >> 6, lane = tid & 63;
  const int l15 = lane & 15, l4 = lane >> 4;
  const int wm = wave >> 1, wn = wave & 1;
  const size_t ra0 = (size_t)blockIdx.y * 128;
  const size_t rb0 = (size_t)blockIdx.x * 128;
  f32x4 acc[4][4] = {};
  for (int k0 = 0; k0 < K; k0 += 32) {
    __syncthreads();
#pragma unroll
    for (int i = 0; i < 2; i++) {
      int s = i * 256 + tid;
      int r = s >> 2, c8 = (s & 3) * 8;
      gload16(A + (ra0 + r) * (size_t)K + k0 + c8, &As[(i * 256 + wave * 64) * 8]);
      gload16(Bm + (rb0 + r) * (size_t)K + k0 + c8, &Bs[(i * 256 + wave * 64) * 8]);
    }
    __syncthreads();
    bf16x8 af[4], bfr[4];
#pragma unroll
    for (int mi = 0; mi < 4; mi++) af[mi] = ld_frag(&As[(wm * 64 + mi * 16 + l15) * 32 + l4 * 8]);
#pragma unroll
    for (int ni = 0; ni < 4; ni++) bfr[ni] = ld_frag(&Bs[(wn * 64 + ni * 16 + l15) * 32 + l4 * 8]);
#pragma unroll
    for (int mi = 0; mi < 4; mi++)
#pragma unroll
      for (int ni = 0; ni < 4; ni++)
        acc[mi][ni] = __builtin_amdgcn_mfma_f32_16x16x32_bf16(af[mi], bfr[ni], acc[mi][ni], 0, 0, 0);
  }
  const int col0 = blockIdx.x * 128 + wn * 64;
  const int row0 = blockIdx.y * 128 + wm * 64;
#pragma unroll
  for (int ni = 0; ni < 4; ni++) {
    int col = col0 + ni * 16 + l15;
    float bv = bias[col];
#pragma unroll
    for (int mi = 0; mi < 4; mi++) {
      int row = row0 + mi * 16 + l4 * 4;
#pragma unroll
      for (int r = 0; r < 4; r++) {
        float v = acc[mi][ni][r] + bv;
        if (OUT_BF16)
          ((unsigned short*)Cv)[(size_t)(row + r) * N + col] = f2bf(v);
        else
          ((float*)Cv)[(size_t)(row + r) * N + col] = v;
      }
    }
  }
}

// ------- in-place L2 normalize K rows (strided layout inside qkv) -------
__global__ void qknorm_s_k(unsigned short* __restrict__ qkv) {
  int row = blockIdx.x * 4 + (threadIdx.x >> 6);  // token*16+head
  int lane = threadIdx.x & 63;
  int t = row >> 4, h = row & 15;
  unsigned* p = (unsigned*)(qkv + (size_t)t * QKVS + 2048 + h * HD);
  unsigned w = p[lane];
  float a = bf2f((unsigned short)(w & 0xffff));
  float b = bf2f((unsigned short)(w >> 16));
  float ss = a * a + b * b;
#pragma unroll
  for (int m = 1; m < 64; m <<= 1) ss += __shfl_xor(ss, m);
  float inv = 1.0f / (sqrtf(ss) + 1e-6f);
  p[lane] = packbf(a * inv, b * inv);
}

// ---- V transpose: Vt[bh][d][l] = qkv[b,l][4096 + h*HD + d] ----
__global__ void vtrans_k(const unsigned short* __restrict__ QKV, unsigned short* __restrict__ Vt) {
  __shared__ unsigned short t[128 * 136];
  const int bh = blockIdx.y, b = bh >> 4, h = bh & 15;
  const int l0 = blockIdx.x * 128;
  const int tid = threadIdx.x;
#pragma unroll
  for (int i = 0; i < 8; i++) {
    int s = i * 256 + tid;
    int r = s >> 4, c8 = (s & 15) * 8;
    uint4 v = *(const uint4*)(QKV + ((size_t)(b * LSEQ + l0 + r)) * QKVS + 4096 + h * HD + c8);
    *(uint4*)&t[r * 136 + c8] = v;
  }
  __syncthreads();
#pragma unroll
  for (int i = 0; i < 8; i++) {
    int s = i * 256 + tid;
    int dd = s >> 4, l8 = (s & 15) * 8;
    unsigned short tmp[8];
#pragma unroll
    for (int j = 0; j < 8; j++) tmp[j] = t[(l8 + j) * 136 + dd];
    *(uint4*)(Vt + ((size_t)bh * HD + dd) * LSEQ + l0 + l8) = *(const uint4*)tmp;
  }
}

// ---------------- attention v4 ----------------
// Swapped QK^T: P[kv][q] in registers -> shuffle to PV A-fragment (no P LDS).
// Double-buffered K/V, ONE barrier per tile. KVBLK=32, KV-split x2, grid 1024.
__global__ __launch_bounds__(256) void attn4_k(
    const unsigned short* __restrict__ QKV, const unsigned short* __restrict__ Vt,
    unsigned short* __restrict__ Na, unsigned short* __restrict__ Nb,
    float* __restrict__ Dw) {
  __shared__ __align__(16) unsigned short Ks[2][32 * 128];  // pitch 256B, XOR (row&7)<<4
  __shared__ __align__(16) unsigned short Vs[2][128 * 40];  // pitch 80B, no XOR (2-way free)

  const int id = blockIdx.x;
  const int xcd = id & 7, sl = id >> 3;     // sl in 0..127
  const int bh = xcd * 4 + (sl >> 5);
  const int kvh = (sl >> 4) & 1, qb = sl & 15;
  const int b = bh >> 4, h = bh & 15;
  const int q0 = qb * 128;
  const int kvbase = kvh * (LSEQ / 2);
  const int tid = threadIdx.x, wave = tid >> 6, lane = tid & 63;
  const int l15 = lane & 15, l4 = lane >> 4;
  const float scale = 0.08838834764831845f;  // 1/sqrt(128)

  // ---- load Q (32 rows/wave) + fused L2 norm ----
  bf16x8 qf[2][4];
#pragma unroll
  for (int rg = 0; rg < 2; rg++) {
    const unsigned short* qp =
        QKV + ((size_t)(b * LSEQ + q0 + wave * 32 + rg * 16 + l15)) * QKVS + h * HD + l4 * 8;
    uint4 qv[4];
    float qs[4][8];
    float ss = 0.f;
#pragma unroll
    for (int kk = 0; kk < 4; kk++) qv[kk] = *(const uint4*)(qp + kk * 32);
#pragma unroll
    for (int kk = 0; kk < 4; kk++) {
      const unsigned* w = (const unsigned*)&qv[kk];
#pragma unroll
      for (int m = 0; m < 4; m++) {
        float a = bf2f((unsigned short)(w[m] & 0xffff));
        float c = bf2f((unsigned short)(w[m] >> 16));
        qs[kk][2 * m] = a; qs[kk][2 * m + 1] = c;
        ss += a * a + c * c;
      }
    }
    ss += __shfl_xor(ss, 16);
    ss += __shfl_xor(ss, 32);
    float inv = 1.0f / (sqrtf(ss) + 1e-6f);
    uint4 qo;
    unsigned* wo = (unsigned*)&qo;
#pragma unroll
    for (int kk = 0; kk < 4; kk++) {
#pragma unroll
      for (int m = 0; m < 4; m++)
        wo[m] = packbf(qs[kk][2 * m] * inv, qs[kk][2 * m + 1] * inv);
      qf[rg][kk] = __builtin_bit_cast(bf16x8, qo);
    }
  }

  f32x4 oacc[2][8] = {};
  float den[2] = {0.f, 0.f};
  uint4 pk[2], pv[2];

  const unsigned short* Kb = QKV + ((size_t)(b * LSEQ)) * QKVS + 2048 + h * HD;
  const unsigned short* Vb = Vt + ((size_t)bh * HD) * LSEQ;
  const int kr0 = tid >> 4, kc = tid & 15;  // K tile 32x128: rows kr0, kr0+16
  const int vr0 = tid >> 2, vc = tid & 3;   // V tile 128x32: rows vr0, vr0+64
  // shuffle sources for P redistribution (see derivation in round notes)
  const int srcA = ((l4 * 2) & 3) * 16 + l15;
  const int srcB = ((l4 * 2 + 1) & 3) * 16 + l15;
  const bool hiSel = (l4 >= 2);

  // prologue: load tile 0 and stage into buffer 0
#pragma unroll
  for (int i = 0; i < 2; i++) {
    pk[i] = *(const uint4*)(Kb + (size_t)(kvbase + kr0 + i * 16) * QKVS + kc * 8);
    pv[i] = *(const uint4*)(Vb + (size_t)(vr0 + i * 64) * LSEQ + kvbase + vc * 8);
  }
#pragma unroll
  for (int i = 0; i < 2; i++) {
    int kr = kr0 + i * 16;
    *(uint4*)((char*)&Ks[0][0] + kr * 256 + ((kc ^ (kr & 7)) << 4)) = pk[i];
    int vr = vr0 + i * 64;
    *(uint4*)((char*)&Vs[0][0] + vr * 80 + vc * 16) = pv[i];
  }

  for (int t = 0; t < 32; t++) {
    const int cur = t & 1;
    __syncthreads();  // buf[cur] staged; buf[cur^1] free
    // issue next-tile loads (latency hidden under compute)
    if (t + 1 < 32) {
      const int kvn = kvbase + (t + 1) * 32;
#pragma unroll
      for (int i = 0; i < 2; i++) {
        pk[i] = *(const uint4*)(Kb + (size_t)(kvn + kr0 + i * 16) * QKVS + kc * 8);
        pv[i] = *(const uint4*)(Vb + (size_t)(vr0 + i * 64) * LSEQ + kvn + vc * 8);
      }
    }

    // ---- swapped QK^T: sacc[rg][ni] = P[kv=ni*16+l4*4+r][q=l15] ----
    f32x4 sacc[2][2] = {};
    char* ksb = (char*)&Ks[cur][0];
    __builtin_amdgcn_s_setprio(1);
#pragma unroll
    for (int ni = 0; ni < 2; ni++) {
#pragma unroll
      for (int kk = 0; kk < 4; kk++) {
        bf16x8 kf = ld_frag(ksb + (ni * 16 + l15) * 256 + (((kk * 4 + l4) ^ (l15 & 7)) << 4));
        sacc[0][ni] = __builtin_amdgcn_mfma_f32_16x16x32_bf16(kf, qf[0][kk], sacc[0][ni], 0, 0, 0);
        sacc[1][ni] = __builtin_amdgcn_mfma_f32_16x16x32_bf16(kf, qf[1][kk], sacc[1][ni], 0, 0, 0);
      }
    }
    __builtin_amdgcn_s_setprio(0);

    // ---- exp + in-register P -> PV-A fragment (shuffles, no LDS) ----
    bf16x8 pa[2];
#pragma unroll
    for (int rg = 0; rg < 2; rg++) {
      float pe[4], po[4];
#pragma unroll
      for (int r = 0; r < 4; r++) {
        pe[r] = __expf(sacc[rg][0][r] * scale);
        po[r] = __expf(sacc[rg][1][r] * scale);
      }
      den[rg] += (pe[0] + pe[1]) + (pe[2] + pe[3]) + (po[0] + po[1]) + (po[2] + po[3]);
      unsigned c0e = packbf(pe[0], pe[1]), c1e = packbf(pe[2], pe[3]);
      unsigned c0o = packbf(po[0], po[1]), c1o = packbf(po[2], po[3]);
      unsigned a0 = __shfl(c0e, srcA), a1 = __shfl(c0o, srcA);
      unsigned b0 = __shfl(c1e, srcA), b1 = __shfl(c1o, srcA);
      unsigned c0 = __shfl(c0e, srcB), c1 = __shfl(c0o, srcB);
      unsigned d0_ = __shfl(c1e, srcB), d1 = __shfl(c1o, srcB);
      uint4 paw;
      paw.x = hiSel ? a1 : a0;
      paw.y = hiSel ? b1 : b0;
      paw.z = hiSel ? c1 : c0;
      paw.w = hiSel ? d1 : d0_;
      pa[rg] = __builtin_bit_cast(bf16x8, paw);
    }

    // ---- PV: oacc[rg][d0] += P[q][kv] * V[kv][d] ----
    char* vsb = (char*)&Vs[cur][0];
    __builtin_amdgcn_s_setprio(1);
#pragma unroll
    for (int d0 = 0; d0 < 8; d0++) {
      bf16x8 vf = ld_frag(vsb + (d0 * 16 + l15) * 80 + l4 * 16);
      oacc[0][d0] = __builtin_amdgcn_mfma_f32_16x16x32_bf16(pa[0], vf, oacc[0][d0], 0, 0, 0);
      oacc[1][d0] = __builtin_amdgcn_mfma_f32_16x16x32_bf16(pa[1], vf, oacc[1][d0], 0, 0, 0);
    }
    __builtin_amdgcn_s_setprio(0);

    // ---- stage next tile into the other buffer (waits vmcnt internally) ----
    if (t + 1 < 32) {
      char* ksn = (char*)&Ks[cur ^ 1][0];
      char* vsn = (char*)&Vs[cur ^ 1][0];
#pragma unroll
      for (int i = 0; i < 2; i++) {
        int kr = kr0 + i * 16;
        *(uint4*)(ksn + kr * 256 + ((kc ^ (kr & 7)) << 4)) = pk[i];
        int vr = vr0 + i * 64;
        *(uint4*)(vsn + vr * 80 + vc * 16) = pv[i];
      }
    }
  }

  // den: per-lane holds partial for q=l15; reduce across l4 groups
  unsigned short* Np = kvh ? Nb : Na;
#pragma unroll
  for (int rg = 0; rg < 2; rg++) {
    float sd = den[rg];
    sd += __shfl_xor(sd, 16);
    sd += __shfl_xor(sd, 32);
    if (l4 == 0) {
      int token = b * LSEQ + q0 + wave * 32 + rg * 16 + l15;
      Dw[((size_t)kvh * MTOK + token) * NH + h] = sd;
    }
  }
#pragma unroll
  for (int rg = 0; rg < 2; rg++)
#pragma unroll
    for (int d0 = 0; d0 < 8; d0++)
#pragma unroll
      for (int r = 0; r < 4; r++) {
        int token = b * LSEQ + q0 + wave * 32 + rg * 16 + l4 * 4 + r;
        Np[(size_t)token * DM + h * HD + d0 * 16 + l15] = f2bf(oacc[rg][d0][r]);
      }
}

// ---------------- combine: ao = (n0+n1)/(d0+d1) ----------------
__global__ void comb_k(const unsigned short* __restrict__ Na,
                       const unsigned short* __restrict__ Nb,
                       const float* __restrict__ Dw, unsigned short* __restrict__ Ao) {
  int i = blockIdx.x * 256 + threadIdx.x;  // 1,048,576 total (8 elems each)
  int token = i >> 8, c8 = i & 255;
  int h = c8 >> 4;
  float d = Dw[(size_t)token * NH + h] + Dw[(size_t)(MTOK + token) * NH + h];
  float inv = 1.0f / d;
  uint4 w0 = ((const uint4*)Na)[i];
  uint4 w1 = ((const uint4*)Nb)[i];
  const unsigned* a = (const unsigned*)&w0;
  const unsigned* bq = (const unsigned*)&w1;
  uint4 o;
  unsigned* ow = (unsigned*)&o;
#pragma unroll
  for (int m = 0; m < 4; m++) {
    float lo = (bf2f((unsigned short)(a[m] & 0xffff)) + bf2f((unsigned short)(bq[m] & 0xffff))) * inv;
    float hi = (bf2f((unsigned short)(a[m] >> 16)) + bf2f((unsigned short)(bq[m] >> 16))) * inv;
    ow[m] = packbf(lo, hi);
  }
  ((uint4*)Ao)[i] = o;
}

extern "C" void kernel_launch(void* const* d_in, const int* in_sizes, int n_in,
                              void* d_out, int out_size, void* d_ws, size_t ws_size,
                              hipStream_t stream) {
  const float* x  = (const float*)d_in[0];
  const float* Wq = (const float*)d_in[1];
  const float* bq = (const float*)d_in[2];
  const float* Wk = (const float*)d_in[3];
  const float* bk = (const float*)d_in[4];
  const float* Wv = (const float*)d_in[5];
  const float* bv = (const float*)d_in[6];
  const float* Wo = (const float*)d_in[7];
  const float* bo = (const float*)d_in[8];

  char* ws = (char*)d_ws;
  unsigned short* xb   = (unsigned short*)(ws + 0);          // [0,16M): x bf16 -> num partial A
  unsigned short* wqkv = (unsigned short*)(ws + 16777216);   // [16M,40M): Wq|Wk|Wv bf16
  unsigned short* wob  = (unsigned short*)(ws + 41943040);   // [40M,48M): Wo bf16
  float*          bqkv = (float*)(ws + 50331648);            // [48M,+24K)
  unsigned short* qkv  = (unsigned short*)(ws + 50364416);   // [48.03M,+48M)
  unsigned short* vt   = wqkv;                                // [16M,32M) after QKV gemm
  float*          dwp  = (float*)(ws + 33554432);            // [32M,32.5M) after QKV gemm
  unsigned short* na   = xb;                                  // [0,16M) after QKV gemm
  unsigned short* nb   = (unsigned short*)d_out;              // first 16M of d_out as scratch
  unsigned short* ao   = qkv;                                 // [48.03M,+16M) after attn

  // casts
  cvt_bf16_k<<<4096, 256, 0, stream>>>(x, xb, MTOK * DM / 8);
  cvt_bf16_k<<<2048, 256, 0, stream>>>(Wq, wqkv, DM * DM / 8);
  cvt_bf16_k<<<2048, 256, 0, stream>>>(Wk, wqkv + 2048 * 2048, DM * DM / 8);
  cvt_bf16_k<<<2048, 256, 0, stream>>>(Wv, wqkv + 4096 * 2048, DM * DM / 8);
  cvt_bf16_k<<<2048, 256, 0, stream>>>(Wo, wob, DM * DM / 8);
  bcat_k<<<24, 256, 0, stream>>>(bq, bk, bv, bqkv);

  // fused QKV projection: [4096,6144] = xb * wqkv^T + bqkv
  gemm_bt<1><<<dim3(QKVS / 128, MTOK / 128), 256, 0, stream>>>(xb, wqkv, bqkv, qkv,
                                                               MTOK, QKVS, DM);

  // K-norm in place (Q-norm fused in attn)
  qknorm_s_k<<<MTOK * NH / 4, 256, 0, stream>>>(qkv);

  // V transpose per head (into dead weight buffer)
  vtrans_k<<<dim3(LSEQ / 128, NB * NH), 256, 0, stream>>>(qkv, vt);

  // attention v4 with KV-split x2
  attn4_k<<<1024, 256, 0, stream>>>(qkv, vt, na, nb, dwp);

  // combine partials -> ao (bf16)
  comb_k<<<4096, 256, 0, stream>>>(na, nb, dwp, ao);

  // output projection (f32 out)
  gemm_bt<0><<<dim3(DM / 128, MTOK / 128), 256, 0, stream>>>(ao, wob, bo, (float*)d_out,
                                                             MTOK, DM, DM);
}